// Round 3
// baseline (417.553 us; speedup 1.0000x reference)
//
#include <hip/hip_runtime.h>
#include <hip/hip_bf16.h>

#define DD 128

// ---------------- max depth reduction ----------------
__global__ void k_depthmax(const int* __restrict__ depths, int* __restrict__ maxd, int n){
  int v = 0;
  for (int i = blockIdx.x * blockDim.x + threadIdx.x; i < n; i += gridDim.x * blockDim.x){
    int d = depths[i]; v = d > v ? d : v;
  }
  #pragma unroll
  for (int off = 32; off; off >>= 1){ int o = __shfl_xor(v, off); v = o > v ? o : v; }
  if ((threadIdx.x & 63) == 0) atomicMax(maxd, v);
}

// ---------------- gate MLP: scale_weights (sw[3]), init lc = ba ----------------
__global__ void k_gate(const int* __restrict__ maxd, const float* __restrict__ Wg1,
                       const float* __restrict__ bg1, const float* __restrict__ Wg2,
                       const float* __restrict__ bg2, const float* __restrict__ ba,
                       float* __restrict__ sw, float* __restrict__ lc, float sf0){
  __shared__ float h[32];
  int t = threadIdx.x;
  float sf1 = (float)(*maxd) / 20.0f;
  if (t < 32) h[t] = fmaxf(0.0f, sf0 * Wg1[t] + sf1 * Wg1[32 + t] + bg1[t]);
  __syncthreads();
  if (t < 3){
    float s = bg2[t];
    for (int k = 0; k < 32; ++k) s += h[k] * Wg2[k * 3 + t];
    sw[t] = 1.0f / (1.0f + __expf(-s));
    lc[t] = ba[t];
  }
}

// ---------------- combined matrices V_i = sw_i * Wh_i @ Wf_i,  ob_i = sw_i * bh_i @ Wf_i ----------------
__global__ void k_combine(const float* __restrict__ Wh, const float* __restrict__ bh,
                          const float* __restrict__ Wf, const float* __restrict__ sw,
                          float* __restrict__ V, float* __restrict__ ob){
  int k = blockIdx.x;        // 0..128 (128 == bias row)
  int i = blockIdx.y;        // hop
  int c = threadIdx.x;       // 0..127
  float s = sw[i];
  float acc = 0.0f;
  if (k < DD){
    for (int d = 0; d < DD; ++d)
      acc += Wh[(i * DD + k) * DD + d] * Wf[(i * DD + d) * DD + c];
    V[(i * DD + k) * DD + c] = s * acc;
  } else {
    for (int d = 0; d < DD; ++d)
      acc += bh[i * DD + d] * Wf[(i * DD + d) * DD + c];
    ob[i * DD + c] = s * acc;
  }
}

// ---------------- U_i = sw_i * Wh_i @ Wa_i  and lc += sw_i * bh_i @ Wa_i ----------------
__global__ void k_ua(const float* __restrict__ Wh, const float* __restrict__ bh,
                     const float* __restrict__ Wa, const float* __restrict__ sw,
                     float* __restrict__ U, float* __restrict__ lc){
  int i = blockIdx.x, k = threadIdx.x;
  float s = sw[i];
  float a0 = 0, a1 = 0, a2 = 0;
  for (int d = 0; d < DD; ++d){
    float w = Wh[(i * DD + k) * DD + d];
    a0 += w * Wa[(i * DD + d) * 3 + 0];
    a1 += w * Wa[(i * DD + d) * 3 + 1];
    a2 += w * Wa[(i * DD + d) * 3 + 2];
  }
  U[(i * DD + k) * 3 + 0] = s * a0;
  U[(i * DD + k) * 3 + 1] = s * a1;
  U[(i * DD + k) * 3 + 2] = s * a2;
  if (k < 3){
    float b = 0;
    for (int d = 0; d < DD; ++d) b += bh[i * DD + d] * Wa[(i * DD + d) * 3 + k];
    atomicAdd(&lc[k], s * b);
  }
}

// ---------------- CSR build ----------------
__global__ void k_hist(const int* __restrict__ col, int* __restrict__ cnt, int e){
  for (int i = blockIdx.x * blockDim.x + threadIdx.x; i < e; i += gridDim.x * blockDim.x)
    atomicAdd(&cnt[col[i]], 1);
}

__global__ void k_scan(const int* __restrict__ cnt, int* __restrict__ offs,
                       int* __restrict__ cur, int n){
  __shared__ int sdata[1024];
  __shared__ int base;
  int t = threadIdx.x;
  if (t == 0) base = 0;
  __syncthreads();
  for (int start = 0; start < n; start += 1024){
    int i = start + t;
    int v = (i < n) ? cnt[i] : 0;
    sdata[t] = v;
    __syncthreads();
    for (int d = 1; d < 1024; d <<= 1){
      int addv = (t >= d) ? sdata[t - d] : 0;
      __syncthreads();
      sdata[t] += addv;
      __syncthreads();
    }
    int incl = sdata[t];
    int b = base;
    if (i < n){ int ex = b + incl - v; offs[i] = ex; cur[i] = ex; }
    int tot = sdata[1023];
    __syncthreads();
    if (t == 0) base = b + tot;
    __syncthreads();
  }
  if (t == 0) offs[n] = base;
}

__global__ void k_fill(const int* __restrict__ row, const int* __restrict__ col,
                       int* __restrict__ cur, int* __restrict__ srcs, int e){
  for (int i = blockIdx.x * blockDim.x + threadIdx.x; i < e; i += gridDim.x * blockDim.x){
    int c = col[i];
    int p = atomicAdd(&cur[c], 1);
    srcs[p] = row[i];
  }
}

// ---------------- scatter_mean as per-node gather: one wave per node, ILP-unrolled ----------------
__global__ void k_agg(const float* __restrict__ src, float* __restrict__ dst,
                      const int* __restrict__ offs, const int* __restrict__ srcs, int n){
  int wid = (blockIdx.x * blockDim.x + threadIdx.x) >> 6;
  int lane = threadIdx.x & 63;
  int nw = (gridDim.x * blockDim.x) >> 6;
  const float2* s2 = (const float2*)src;
  for (int node = wid; node < n; node += nw){
    int o0 = offs[node], o1 = offs[node + 1];
    float ax = 0.0f, ay = 0.0f;
    for (int base = o0; base < o1; base += 64){
      int m = o1 - base; if (m > 64) m = 64;
      int myidx = (base + lane < o1) ? srcs[base + lane] : 0;
      int j = 0;
      for (; j + 4 <= m; j += 4){
        int i0 = __shfl(myidx, j);
        int i1 = __shfl(myidx, j + 1);
        int i2 = __shfl(myidx, j + 2);
        int i3 = __shfl(myidx, j + 3);
        float2 v0 = s2[(size_t)i0 * 64 + lane];
        float2 v1 = s2[(size_t)i1 * 64 + lane];
        float2 v2 = s2[(size_t)i2 * 64 + lane];
        float2 v3 = s2[(size_t)i3 * 64 + lane];
        ax += (v0.x + v1.x) + (v2.x + v3.x);
        ay += (v0.y + v1.y) + (v2.y + v3.y);
      }
      for (; j < m; ++j){
        int s = __shfl(myidx, j);
        float2 v = s2[(size_t)s * 64 + lane];
        ax += v.x; ay += v.y;
      }
    }
    float inv = 1.0f / fmaxf((float)(o1 - o0), 1.0f);
    ((float2*)dst)[(size_t)node * 64 + lane] = make_float2(ax * inv, ay * inv);
  }
}

// ---------------- attention: logits = sum_i c_i @ U_i + lc ; softmax ----------------
__global__ void k_att(const float* __restrict__ c0, const float* __restrict__ c1,
                      const float* __restrict__ c2, const float* __restrict__ U,
                      const float* __restrict__ lc, float* __restrict__ att, int n){
  int wid = (blockIdx.x * blockDim.x + threadIdx.x) >> 6;
  int lane = threadIdx.x & 63;
  int nw = (gridDim.x * blockDim.x) >> 6;
  for (int node = wid; node < n; node += nw){
    float l0 = 0, l1 = 0, l2 = 0;
    {
      float2 v = ((const float2*)c0)[(size_t)node * 64 + lane];
      int k0 = (0 * DD + lane * 2) * 3;
      l0 += v.x * U[k0 + 0] + v.y * U[k0 + 3];
      l1 += v.x * U[k0 + 1] + v.y * U[k0 + 4];
      l2 += v.x * U[k0 + 2] + v.y * U[k0 + 5];
    }
    {
      float2 v = ((const float2*)c1)[(size_t)node * 64 + lane];
      int k0 = (1 * DD + lane * 2) * 3;
      l0 += v.x * U[k0 + 0] + v.y * U[k0 + 3];
      l1 += v.x * U[k0 + 1] + v.y * U[k0 + 4];
      l2 += v.x * U[k0 + 2] + v.y * U[k0 + 5];
    }
    {
      float2 v = ((const float2*)c2)[(size_t)node * 64 + lane];
      int k0 = (2 * DD + lane * 2) * 3;
      l0 += v.x * U[k0 + 0] + v.y * U[k0 + 3];
      l1 += v.x * U[k0 + 1] + v.y * U[k0 + 4];
      l2 += v.x * U[k0 + 2] + v.y * U[k0 + 5];
    }
    #pragma unroll
    for (int off = 32; off; off >>= 1){
      l0 += __shfl_xor(l0, off);
      l1 += __shfl_xor(l1, off);
      l2 += __shfl_xor(l2, off);
    }
    l0 += lc[0]; l1 += lc[1]; l2 += lc[2];
    float m = fmaxf(l0, fmaxf(l1, l2));
    float e0 = __expf(l0 - m), e1 = __expf(l1 - m), e2 = __expf(l2 - m);
    float inv = 1.0f / (e0 + e1 + e2);
    if (lane == 0)
      *(float4*)(att + (size_t)node * 4) = make_float4(e0 * inv, e1 * inv, e2 * inv, 0.0f);
  }
}

// ---------------- fused output GEMM: out = Z @ Vbig + (att·ob + bf) ----------------
// Z[n, i*128+k] = att[n][i] * c_i[n][k], formed at staging time.
__global__ __launch_bounds__(256) void k_out(
    const float* __restrict__ c0, const float* __restrict__ c1, const float* __restrict__ c2,
    const float* __restrict__ att, const float* __restrict__ V, const float* __restrict__ ob,
    const float* __restrict__ bf, float* __restrict__ out, int n){
  __shared__ float Ct[64][68];    // 64 nodes x 64 k (padded)
  __shared__ float Vt[64][128];   // 64 k x 128 cols
  int nbase = blockIdx.x * 64;
  int t = threadIdx.x;
  int tIdN = t >> 5;      // 0..7  -> node group of 8
  int tIdC = t & 31;      // 0..31 -> col group of 4
  float acc[8][4];
  #pragma unroll
  for (int a = 0; a < 8; ++a)
    #pragma unroll
    for (int b = 0; b < 4; ++b) acc[a][b] = 0.0f;

  for (int kt = 0; kt < 6; ++kt){
    int i = kt >> 1;
    int kc0 = (kt & 1) << 6;
    const float* cp = (i == 0) ? c0 : (i == 1) ? c1 : c2;
    __syncthreads();
    // stage Z tile (att folded in)
    {
      int r = t >> 4;            // 0..15
      int cq = (t & 15) << 2;    // 0..60
      #pragma unroll
      for (int p = 0; p < 4; ++p){
        int rr = r + p * 16;
        int gn = nbase + rr;
        float4 v = make_float4(0, 0, 0, 0);
        float a = 0.0f;
        if (gn < n){
          v = *(const float4*)(cp + (size_t)gn * DD + kc0 + cq);
          a = att[gn * 4 + i];
        }
        *(float4*)(&Ct[rr][cq]) = make_float4(v.x * a, v.y * a, v.z * a, v.w * a);
      }
    }
    // stage V tile
    {
      int vr = t >> 5;           // 0..7
      int vc = (t & 31) << 2;    // 0..124
      #pragma unroll
      for (int p = 0; p < 8; ++p){
        int rr = vr + p * 8;
        *(float4*)(&Vt[rr][vc]) = *(const float4*)(V + (size_t)(i * DD + kc0 + rr) * DD + vc);
      }
    }
    __syncthreads();
    // GEMM on the tile
    for (int kk = 0; kk < 64; kk += 4){
      float4 z[8];
      #pragma unroll
      for (int nn = 0; nn < 8; ++nn) z[nn] = *(const float4*)(&Ct[tIdN * 8 + nn][kk]);
      #pragma unroll
      for (int q = 0; q < 4; ++q){
        float4 v = *(const float4*)(&Vt[kk + q][tIdC * 4]);
        #pragma unroll
        for (int nn = 0; nn < 8; ++nn){
          float zz = (q == 0) ? z[nn].x : (q == 1) ? z[nn].y : (q == 2) ? z[nn].z : z[nn].w;
          acc[nn][0] += zz * v.x;
          acc[nn][1] += zz * v.y;
          acc[nn][2] += zz * v.z;
          acc[nn][3] += zz * v.w;
        }
      }
    }
  }
  // epilogue: bias + attention-weighted ob
  int cc = tIdC * 4;
  float4 bb = *(const float4*)(bf + cc);
  float4 o0 = *(const float4*)(ob + 0 * DD + cc);
  float4 o1 = *(const float4*)(ob + 1 * DD + cc);
  float4 o2 = *(const float4*)(ob + 2 * DD + cc);
  #pragma unroll
  for (int nn = 0; nn < 8; ++nn){
    int gn = nbase + tIdN * 8 + nn;
    if (gn < n){
      float a0 = att[gn * 4 + 0], a1 = att[gn * 4 + 1], a2 = att[gn * 4 + 2];
      float4 r;
      r.x = acc[nn][0] + bb.x + a0 * o0.x + a1 * o1.x + a2 * o2.x;
      r.y = acc[nn][1] + bb.y + a0 * o0.y + a1 * o1.y + a2 * o2.y;
      r.z = acc[nn][2] + bb.z + a0 * o0.z + a1 * o1.z + a2 * o2.z;
      r.w = acc[nn][3] + bb.w + a0 * o0.w + a1 * o1.w + a2 * o2.w;
      *(float4*)(out + (size_t)gn * DD + cc) = r;
    }
  }
}

extern "C" void kernel_launch(void* const* d_in, const int* in_sizes, int n_in,
                              void* d_out, int out_size, void* d_ws, size_t ws_size,
                              hipStream_t stream){
  const float* x   = (const float*)d_in[0];
  const int*   ei  = (const int*)d_in[1];
  const int*   dep = (const int*)d_in[2];
  const float* Wh  = (const float*)d_in[3];
  const float* bh  = (const float*)d_in[4];
  const float* Wg1 = (const float*)d_in[5];
  const float* bg1 = (const float*)d_in[6];
  const float* Wg2 = (const float*)d_in[7];
  const float* bg2 = (const float*)d_in[8];
  const float* Wa  = (const float*)d_in[9];
  const float* ba  = (const float*)d_in[10];
  const float* Wf  = (const float*)d_in[11];
  const float* bf  = (const float*)d_in[12];
  float* out = (float*)d_out;

  int N = in_sizes[0] / DD;
  int E = in_sizes[1] / 2;
  if (N <= 0) return;
  const int* row = ei;
  const int* col = ei + E;

  char* w = (char*)d_ws;
  size_t o = 0;
  auto alloc = [&](size_t bytes) -> void* {
    void* p = w + o;
    o += (bytes + 255) & ~(size_t)255;
    return p;
  };
  float* c1   = (float*)alloc((size_t)N * DD * 4);
  float* c2   = (float*)alloc((size_t)N * DD * 4);
  float* att  = (float*)alloc((size_t)N * 4 * 4);
  float* V    = (float*)alloc((size_t)3 * DD * DD * 4);
  float* ob   = (float*)alloc((size_t)3 * DD * 4);
  float* U    = (float*)alloc((size_t)3 * DD * 3 * 4);
  float* lc   = (float*)alloc(16);
  float* sw   = (float*)alloc(16);
  int*   maxd = (int*)alloc(16);
  int*   cnt  = (int*)alloc((size_t)N * 4);
  int*   offs = (int*)alloc((size_t)(N + 1) * 4);
  int*   cur  = (int*)alloc((size_t)N * 4);
  int*   srcs = (int*)alloc((size_t)E * 4);

  hipMemsetAsync(maxd, 0, 4, stream);
  hipMemsetAsync(cnt, 0, (size_t)N * 4, stream);

  k_depthmax<<<128, 256, 0, stream>>>(dep, maxd, N);
  k_gate<<<1, 64, 0, stream>>>(maxd, Wg1, bg1, Wg2, bg2, ba, sw, lc, (float)N / 5000.0f);
  k_combine<<<dim3(129, 3), 128, 0, stream>>>(Wh, bh, Wf, sw, V, ob);
  k_ua<<<3, 128, 0, stream>>>(Wh, bh, Wa, sw, U, lc);
  k_hist<<<(E + 255) / 256, 256, 0, stream>>>(col, cnt, E);
  k_scan<<<1, 1024, 0, stream>>>(cnt, offs, cur, N);
  k_fill<<<(E + 255) / 256, 256, 0, stream>>>(row, col, cur, srcs, E);
  int aggBlocks = (N + 3) / 4;
  k_agg<<<aggBlocks, 256, 0, stream>>>(x, c1, offs, srcs, N);
  k_agg<<<aggBlocks, 256, 0, stream>>>(c1, c2, offs, srcs, N);
  k_att<<<aggBlocks, 256, 0, stream>>>(x, c1, c2, U, lc, att, N);
  k_out<<<(N + 63) / 64, 256, 0, stream>>>(x, c1, c2, att, V, ob, bf, out, N);
}

// Round 5
// 339.940 us; speedup vs baseline: 1.2283x; 1.2283x over previous
//
#include <hip/hip_runtime.h>
#include <hip/hip_bf16.h>

#define DD 128

// ---------------- max depth reduction ----------------
__global__ void k_depthmax(const int* __restrict__ depths, int* __restrict__ maxd, int n){
  int v = 0;
  for (int i = blockIdx.x * blockDim.x + threadIdx.x; i < n; i += gridDim.x * blockDim.x){
    int d = depths[i]; v = d > v ? d : v;
  }
  #pragma unroll
  for (int off = 32; off; off >>= 1){ int o = __shfl_xor(v, off); v = o > v ? o : v; }
  if ((threadIdx.x & 63) == 0) atomicMax(maxd, v);
}

// ---------------- gate MLP: scale_weights (sw[3]), init lc = ba ----------------
__global__ void k_gate(const int* __restrict__ maxd, const float* __restrict__ Wg1,
                       const float* __restrict__ bg1, const float* __restrict__ Wg2,
                       const float* __restrict__ bg2, const float* __restrict__ ba,
                       float* __restrict__ sw, float* __restrict__ lc, float sf0){
  __shared__ float h[32];
  int t = threadIdx.x;
  float sf1 = (float)(*maxd) / 20.0f;
  if (t < 32) h[t] = fmaxf(0.0f, sf0 * Wg1[t] + sf1 * Wg1[32 + t] + bg1[t]);
  __syncthreads();
  if (t < 3){
    float s = bg2[t];
    for (int k = 0; k < 32; ++k) s += h[k] * Wg2[k * 3 + t];
    sw[t] = 1.0f / (1.0f + __expf(-s));
    lc[t] = ba[t];
  }
}

// ---------------- combined matrices V_i = sw_i * Wh_i @ Wf_i,  ob_i = sw_i * bh_i @ Wf_i ----------------
__global__ void k_combine(const float* __restrict__ Wh, const float* __restrict__ bh,
                          const float* __restrict__ Wf, const float* __restrict__ sw,
                          float* __restrict__ V, float* __restrict__ ob){
  int k = blockIdx.x;        // 0..128 (128 == bias row)
  int i = blockIdx.y;        // hop
  int c = threadIdx.x;       // 0..127
  float s = sw[i];
  float acc = 0.0f;
  if (k < DD){
    for (int d = 0; d < DD; ++d)
      acc += Wh[(i * DD + k) * DD + d] * Wf[(i * DD + d) * DD + c];
    V[(i * DD + k) * DD + c] = s * acc;
  } else {
    for (int d = 0; d < DD; ++d)
      acc += bh[i * DD + d] * Wf[(i * DD + d) * DD + c];
    ob[i * DD + c] = s * acc;
  }
}

// ---------------- U_i = sw_i * Wh_i @ Wa_i  and lc += sw_i * bh_i @ Wa_i ----------------
__global__ void k_ua(const float* __restrict__ Wh, const float* __restrict__ bh,
                     const float* __restrict__ Wa, const float* __restrict__ sw,
                     float* __restrict__ U, float* __restrict__ lc){
  int i = blockIdx.x, k = threadIdx.x;
  float s = sw[i];
  float a0 = 0, a1 = 0, a2 = 0;
  for (int d = 0; d < DD; ++d){
    float w = Wh[(i * DD + k) * DD + d];
    a0 += w * Wa[(i * DD + d) * 3 + 0];
    a1 += w * Wa[(i * DD + d) * 3 + 1];
    a2 += w * Wa[(i * DD + d) * 3 + 2];
  }
  U[(i * DD + k) * 3 + 0] = s * a0;
  U[(i * DD + k) * 3 + 1] = s * a1;
  U[(i * DD + k) * 3 + 2] = s * a2;
  if (k < 3){
    float b = 0;
    for (int d = 0; d < DD; ++d) b += bh[i * DD + d] * Wa[(i * DD + d) * 3 + k];
    atomicAdd(&lc[k], s * b);
  }
}

// ---------------- CSR build ----------------
__global__ void k_hist(const int* __restrict__ col, int* __restrict__ cnt, int e){
  for (int i = blockIdx.x * blockDim.x + threadIdx.x; i < e; i += gridDim.x * blockDim.x)
    atomicAdd(&cnt[col[i]], 1);
}

// ---- 3-phase parallel scan: block-local scan -> scan of block totals -> add base ----
__global__ void k_scan1(const int* __restrict__ cnt, int* __restrict__ loc,
                        int* __restrict__ btot, int n){
  __shared__ int sdata[1024];
  int t = threadIdx.x;
  int i = blockIdx.x * 1024 + t;
  int v = (i < n) ? cnt[i] : 0;
  sdata[t] = v;
  __syncthreads();
  for (int d = 1; d < 1024; d <<= 1){
    int a = (t >= d) ? sdata[t - d] : 0;
    __syncthreads();
    sdata[t] += a;
    __syncthreads();
  }
  if (i < n) loc[i] = sdata[t] - v;          // block-local exclusive
  if (t == 1023) btot[blockIdx.x] = sdata[1023];
}

__global__ void k_scan2(const int* __restrict__ btot, int* __restrict__ bbase,
                        int nb, int* __restrict__ offs, int n){
  int lane = threadIdx.x & 63;
  int carry = 0;
  for (int s = 0; s < nb; s += 64){
    int idx = s + lane;
    int v = (idx < nb) ? btot[idx] : 0;
    int incl = v;
    #pragma unroll
    for (int d = 1; d < 64; d <<= 1){
      int o = __shfl_up(incl, d);
      if (lane >= d) incl += o;
    }
    if (idx < nb) bbase[idx] = carry + incl - v;
    carry += __shfl(incl, 63);
  }
  if (lane == 0) offs[n] = carry;
}

__global__ void k_scan3(const int* __restrict__ loc, const int* __restrict__ bbase,
                        int* __restrict__ offs, int* __restrict__ cur, int n){
  int i = blockIdx.x * blockDim.x + threadIdx.x;
  if (i < n){
    int ex = loc[i] + bbase[i >> 10];
    offs[i] = ex;
    cur[i] = ex;
  }
}

__global__ void k_fill(const int* __restrict__ row, const int* __restrict__ col,
                       int* __restrict__ cur, int* __restrict__ srcs, int e){
  for (int i = blockIdx.x * blockDim.x + threadIdx.x; i < e; i += gridDim.x * blockDim.x){
    int c = col[i];
    int p = atomicAdd(&cur[c], 1);
    srcs[p] = row[i];
  }
}

// ---------------- scatter_mean as per-node gather: one wave per node, ILP-unrolled ----------------
__global__ void k_agg(const float* __restrict__ src, float* __restrict__ dst,
                      const int* __restrict__ offs, const int* __restrict__ srcs, int n){
  int wid = (blockIdx.x * blockDim.x + threadIdx.x) >> 6;
  int lane = threadIdx.x & 63;
  int nw = (gridDim.x * blockDim.x) >> 6;
  const float2* s2 = (const float2*)src;
  for (int node = wid; node < n; node += nw){
    int o0 = offs[node], o1 = offs[node + 1];
    float ax = 0.0f, ay = 0.0f;
    for (int base = o0; base < o1; base += 64){
      int m = o1 - base; if (m > 64) m = 64;
      int myidx = (base + lane < o1) ? srcs[base + lane] : 0;
      int j = 0;
      for (; j + 4 <= m; j += 4){
        int i0 = __shfl(myidx, j);
        int i1 = __shfl(myidx, j + 1);
        int i2 = __shfl(myidx, j + 2);
        int i3 = __shfl(myidx, j + 3);
        float2 v0 = s2[(size_t)i0 * 64 + lane];
        float2 v1 = s2[(size_t)i1 * 64 + lane];
        float2 v2 = s2[(size_t)i2 * 64 + lane];
        float2 v3 = s2[(size_t)i3 * 64 + lane];
        ax += (v0.x + v1.x) + (v2.x + v3.x);
        ay += (v0.y + v1.y) + (v2.y + v3.y);
      }
      for (; j < m; ++j){
        int s = __shfl(myidx, j);
        float2 v = s2[(size_t)s * 64 + lane];
        ax += v.x; ay += v.y;
      }
    }
    float inv = 1.0f / fmaxf((float)(o1 - o0), 1.0f);
    ((float2*)dst)[(size_t)node * 64 + lane] = make_float2(ax * inv, ay * inv);
  }
}

// ---------------- attention: logits = sum_i c_i @ U_i + lc ; softmax ----------------
__global__ void k_att(const float* __restrict__ c0, const float* __restrict__ c1,
                      const float* __restrict__ c2, const float* __restrict__ U,
                      const float* __restrict__ lc, float* __restrict__ att, int n){
  int wid = (blockIdx.x * blockDim.x + threadIdx.x) >> 6;
  int lane = threadIdx.x & 63;
  int nw = (gridDim.x * blockDim.x) >> 6;
  for (int node = wid; node < n; node += nw){
    float l0 = 0, l1 = 0, l2 = 0;
    {
      float2 v = ((const float2*)c0)[(size_t)node * 64 + lane];
      int k0 = (0 * DD + lane * 2) * 3;
      l0 += v.x * U[k0 + 0] + v.y * U[k0 + 3];
      l1 += v.x * U[k0 + 1] + v.y * U[k0 + 4];
      l2 += v.x * U[k0 + 2] + v.y * U[k0 + 5];
    }
    {
      float2 v = ((const float2*)c1)[(size_t)node * 64 + lane];
      int k0 = (1 * DD + lane * 2) * 3;
      l0 += v.x * U[k0 + 0] + v.y * U[k0 + 3];
      l1 += v.x * U[k0 + 1] + v.y * U[k0 + 4];
      l2 += v.x * U[k0 + 2] + v.y * U[k0 + 5];
    }
    {
      float2 v = ((const float2*)c2)[(size_t)node * 64 + lane];
      int k0 = (2 * DD + lane * 2) * 3;
      l0 += v.x * U[k0 + 0] + v.y * U[k0 + 3];
      l1 += v.x * U[k0 + 1] + v.y * U[k0 + 4];
      l2 += v.x * U[k0 + 2] + v.y * U[k0 + 5];
    }
    #pragma unroll
    for (int off = 32; off; off >>= 1){
      l0 += __shfl_xor(l0, off);
      l1 += __shfl_xor(l1, off);
      l2 += __shfl_xor(l2, off);
    }
    l0 += lc[0]; l1 += lc[1]; l2 += lc[2];
    float m = fmaxf(l0, fmaxf(l1, l2));
    float e0 = __expf(l0 - m), e1 = __expf(l1 - m), e2 = __expf(l2 - m);
    float inv = 1.0f / (e0 + e1 + e2);
    if (lane == 0)
      *(float4*)(att + (size_t)node * 4) = make_float4(e0 * inv, e1 * inv, e2 * inv, 0.0f);
  }
}

// ---------------- fused output GEMM: out = Z @ Vbig + (att·ob + bf) ----------------
// Z[n, i*128+k] = att[n][i] * c_i[n][k], formed at staging time.
__global__ __launch_bounds__(256) void k_out(
    const float* __restrict__ c0, const float* __restrict__ c1, const float* __restrict__ c2,
    const float* __restrict__ att, const float* __restrict__ V, const float* __restrict__ ob,
    const float* __restrict__ bf, float* __restrict__ out, int n){
  __shared__ float Ct[64][68];    // 64 nodes x 64 k (padded)
  __shared__ float Vt[64][128];   // 64 k x 128 cols
  int nbase = blockIdx.x * 64;
  int t = threadIdx.x;
  int tIdN = t >> 5;      // 0..7  -> node group of 8
  int tIdC = t & 31;      // 0..31 -> col group of 4
  float acc[8][4];
  #pragma unroll
  for (int a = 0; a < 8; ++a)
    #pragma unroll
    for (int b = 0; b < 4; ++b) acc[a][b] = 0.0f;

  for (int kt = 0; kt < 6; ++kt){
    int i = kt >> 1;
    int kc0 = (kt & 1) << 6;
    const float* cp = (i == 0) ? c0 : (i == 1) ? c1 : c2;
    __syncthreads();
    // stage Z tile (att folded in)
    {
      int r = t >> 4;            // 0..15
      int cq = (t & 15) << 2;    // 0..60
      #pragma unroll
      for (int p = 0; p < 4; ++p){
        int rr = r + p * 16;
        int gn = nbase + rr;
        float4 v = make_float4(0, 0, 0, 0);
        float a = 0.0f;
        if (gn < n){
          v = *(const float4*)(cp + (size_t)gn * DD + kc0 + cq);
          a = att[gn * 4 + i];
        }
        *(float4*)(&Ct[rr][cq]) = make_float4(v.x * a, v.y * a, v.z * a, v.w * a);
      }
    }
    // stage V tile
    {
      int vr = t >> 5;           // 0..7
      int vc = (t & 31) << 2;    // 0..124
      #pragma unroll
      for (int p = 0; p < 8; ++p){
        int rr = vr + p * 8;
        *(float4*)(&Vt[rr][vc]) = *(const float4*)(V + (size_t)(i * DD + kc0 + rr) * DD + vc);
      }
    }
    __syncthreads();
    // GEMM on the tile
    for (int kk = 0; kk < 64; kk += 4){
      float4 z[8];
      #pragma unroll
      for (int nn = 0; nn < 8; ++nn) z[nn] = *(const float4*)(&Ct[tIdN * 8 + nn][kk]);
      #pragma unroll
      for (int q = 0; q < 4; ++q){
        float4 v = *(const float4*)(&Vt[kk + q][tIdC * 4]);
        #pragma unroll
        for (int nn = 0; nn < 8; ++nn){
          float zz = (q == 0) ? z[nn].x : (q == 1) ? z[nn].y : (q == 2) ? z[nn].z : z[nn].w;
          acc[nn][0] += zz * v.x;
          acc[nn][1] += zz * v.y;
          acc[nn][2] += zz * v.z;
          acc[nn][3] += zz * v.w;
        }
      }
    }
  }
  // epilogue: bias + attention-weighted ob
  int cc = tIdC * 4;
  float4 bb = *(const float4*)(bf + cc);
  float4 o0 = *(const float4*)(ob + 0 * DD + cc);
  float4 o1 = *(const float4*)(ob + 1 * DD + cc);
  float4 o2 = *(const float4*)(ob + 2 * DD + cc);
  #pragma unroll
  for (int nn = 0; nn < 8; ++nn){
    int gn = nbase + tIdN * 8 + nn;
    if (gn < n){
      float a0 = att[gn * 4 + 0], a1 = att[gn * 4 + 1], a2 = att[gn * 4 + 2];
      float4 r;
      r.x = acc[nn][0] + bb.x + a0 * o0.x + a1 * o1.x + a2 * o2.x;
      r.y = acc[nn][1] + bb.y + a0 * o0.y + a1 * o1.y + a2 * o2.y;
      r.z = acc[nn][2] + bb.z + a0 * o0.z + a1 * o1.z + a2 * o2.z;
      r.w = acc[nn][3] + bb.w + a0 * o0.w + a1 * o1.w + a2 * o2.w;
      *(float4*)(out + (size_t)gn * DD + cc) = r;
    }
  }
}

extern "C" void kernel_launch(void* const* d_in, const int* in_sizes, int n_in,
                              void* d_out, int out_size, void* d_ws, size_t ws_size,
                              hipStream_t stream){
  const float* x   = (const float*)d_in[0];
  const int*   ei  = (const int*)d_in[1];
  const int*   dep = (const int*)d_in[2];
  const float* Wh  = (const float*)d_in[3];
  const float* bh  = (const float*)d_in[4];
  const float* Wg1 = (const float*)d_in[5];
  const float* bg1 = (const float*)d_in[6];
  const float* Wg2 = (const float*)d_in[7];
  const float* bg2 = (const float*)d_in[8];
  const float* Wa  = (const float*)d_in[9];
  const float* ba  = (const float*)d_in[10];
  const float* Wf  = (const float*)d_in[11];
  const float* bf  = (const float*)d_in[12];
  float* out = (float*)d_out;

  int N = in_sizes[0] / DD;
  int E = in_sizes[1] / 2;
  if (N <= 0) return;
  const int* row = ei;
  const int* col = ei + E;

  char* w = (char*)d_ws;
  size_t o = 0;
  auto alloc = [&](size_t bytes) -> void* {
    void* p = w + o;
    o += (bytes + 255) & ~(size_t)255;
    return p;
  };
  float* c1   = (float*)alloc((size_t)N * DD * 4);
  float* c2   = (float*)alloc((size_t)N * DD * 4);
  float* att  = (float*)alloc((size_t)N * 4 * 4);
  float* V    = (float*)alloc((size_t)3 * DD * DD * 4);
  float* ob   = (float*)alloc((size_t)3 * DD * 4);
  float* U    = (float*)alloc((size_t)3 * DD * 3 * 4);
  float* lc   = (float*)alloc(16);
  float* sw   = (float*)alloc(16);
  int*   maxd = (int*)alloc(16);
  int*   cnt  = (int*)alloc((size_t)N * 4);
  int*   offs = (int*)alloc((size_t)(N + 1) * 4);
  int*   cur  = (int*)alloc((size_t)N * 4);
  int*   srcs = (int*)alloc((size_t)E * 4);
  int*   loc  = (int*)alloc((size_t)N * 4);
  int    nb   = (N + 1023) / 1024;
  int*   btot = (int*)alloc((size_t)nb * 4);
  int*   bbase= (int*)alloc((size_t)nb * 4);

  hipMemsetAsync(maxd, 0, 4, stream);
  hipMemsetAsync(cnt, 0, (size_t)N * 4, stream);

  k_depthmax<<<128, 256, 0, stream>>>(dep, maxd, N);
  k_gate<<<1, 64, 0, stream>>>(maxd, Wg1, bg1, Wg2, bg2, ba, sw, lc, (float)N / 5000.0f);
  k_combine<<<dim3(129, 3), 128, 0, stream>>>(Wh, bh, Wf, sw, V, ob);
  k_ua<<<3, 128, 0, stream>>>(Wh, bh, Wa, sw, U, lc);
  k_hist<<<(E + 255) / 256, 256, 0, stream>>>(col, cnt, E);
  k_scan1<<<nb, 1024, 0, stream>>>(cnt, loc, btot, N);
  k_scan2<<<1, 64, 0, stream>>>(btot, bbase, nb, offs, N);
  k_scan3<<<(N + 255) / 256, 256, 0, stream>>>(loc, bbase, offs, cur, N);
  k_fill<<<(E + 255) / 256, 256, 0, stream>>>(row, col, cur, srcs, E);
  int aggBlocks = (N + 3) / 4;
  k_agg<<<aggBlocks, 256, 0, stream>>>(x, c1, offs, srcs, N);
  k_agg<<<aggBlocks, 256, 0, stream>>>(c1, c2, offs, srcs, N);
  k_att<<<aggBlocks, 256, 0, stream>>>(x, c1, c2, U, lc, att, N);
  k_out<<<(N + 63) / 64, 256, 0, stream>>>(x, c1, c2, att, V, ob, bf, out, N);
}

// Round 6
// 337.537 us; speedup vs baseline: 1.2371x; 1.0071x over previous
//
#include <hip/hip_runtime.h>
#include <hip/hip_bf16.h>

#define DD 128

// ---------------- max depth reduction ----------------
__global__ void k_depthmax(const int* __restrict__ depths, int* __restrict__ maxd, int n){
  int v = 0;
  for (int i = blockIdx.x * blockDim.x + threadIdx.x; i < n; i += gridDim.x * blockDim.x){
    int d = depths[i]; v = d > v ? d : v;
  }
  #pragma unroll
  for (int off = 32; off; off >>= 1){ int o = __shfl_xor(v, off); v = o > v ? o : v; }
  if ((threadIdx.x & 63) == 0) atomicMax(maxd, v);
}

// ---------------- gate MLP: scale_weights (sw[3]), init lc = ba ----------------
__global__ void k_gate(const int* __restrict__ maxd, const float* __restrict__ Wg1,
                       const float* __restrict__ bg1, const float* __restrict__ Wg2,
                       const float* __restrict__ bg2, const float* __restrict__ ba,
                       float* __restrict__ sw, float* __restrict__ lc, float sf0){
  __shared__ float h[32];
  int t = threadIdx.x;
  float sf1 = (float)(*maxd) / 20.0f;
  if (t < 32) h[t] = fmaxf(0.0f, sf0 * Wg1[t] + sf1 * Wg1[32 + t] + bg1[t]);
  __syncthreads();
  if (t < 3){
    float s = bg2[t];
    for (int k = 0; k < 32; ++k) s += h[k] * Wg2[k * 3 + t];
    sw[t] = 1.0f / (1.0f + __expf(-s));
    lc[t] = ba[t];
  }
}

// ---------------- combined matrices V_i = sw_i * Wh_i @ Wf_i,  ob_i = sw_i * bh_i @ Wf_i ----------------
__global__ void k_combine(const float* __restrict__ Wh, const float* __restrict__ bh,
                          const float* __restrict__ Wf, const float* __restrict__ sw,
                          float* __restrict__ V, float* __restrict__ ob){
  int k = blockIdx.x;        // 0..128 (128 == bias row)
  int i = blockIdx.y;        // hop
  int c = threadIdx.x;       // 0..127
  float s = sw[i];
  float acc = 0.0f;
  if (k < DD){
    for (int d = 0; d < DD; ++d)
      acc += Wh[(i * DD + k) * DD + d] * Wf[(i * DD + d) * DD + c];
    V[(i * DD + k) * DD + c] = s * acc;
  } else {
    for (int d = 0; d < DD; ++d)
      acc += bh[i * DD + d] * Wf[(i * DD + d) * DD + c];
    ob[i * DD + c] = s * acc;
  }
}

// ---------------- U_i = sw_i * Wh_i @ Wa_i  and lc += sw_i * bh_i @ Wa_i ----------------
__global__ void k_ua(const float* __restrict__ Wh, const float* __restrict__ bh,
                     const float* __restrict__ Wa, const float* __restrict__ sw,
                     float* __restrict__ U, float* __restrict__ lc){
  int i = blockIdx.x, k = threadIdx.x;
  float s = sw[i];
  float a0 = 0, a1 = 0, a2 = 0;
  for (int d = 0; d < DD; ++d){
    float w = Wh[(i * DD + k) * DD + d];
    a0 += w * Wa[(i * DD + d) * 3 + 0];
    a1 += w * Wa[(i * DD + d) * 3 + 1];
    a2 += w * Wa[(i * DD + d) * 3 + 2];
  }
  U[(i * DD + k) * 3 + 0] = s * a0;
  U[(i * DD + k) * 3 + 1] = s * a1;
  U[(i * DD + k) * 3 + 2] = s * a2;
  if (k < 3){
    float b = 0;
    for (int d = 0; d < DD; ++d) b += bh[i * DD + d] * Wa[(i * DD + d) * 3 + k];
    atomicAdd(&lc[k], s * b);
  }
}

// ---------------- CSR build ----------------
__global__ void k_hist(const int* __restrict__ col, int* __restrict__ cnt, int e){
  for (int i = blockIdx.x * blockDim.x + threadIdx.x; i < e; i += gridDim.x * blockDim.x)
    atomicAdd(&cnt[col[i]], 1);
}

// ---- 3-phase parallel scan: block-local scan -> scan of block totals -> add base ----
__global__ void k_scan1(const int* __restrict__ cnt, int* __restrict__ loc,
                        int* __restrict__ btot, int n){
  __shared__ int sdata[1024];
  int t = threadIdx.x;
  int i = blockIdx.x * 1024 + t;
  int v = (i < n) ? cnt[i] : 0;
  sdata[t] = v;
  __syncthreads();
  for (int d = 1; d < 1024; d <<= 1){
    int a = (t >= d) ? sdata[t - d] : 0;
    __syncthreads();
    sdata[t] += a;
    __syncthreads();
  }
  if (i < n) loc[i] = sdata[t] - v;          // block-local exclusive
  if (t == 1023) btot[blockIdx.x] = sdata[1023];
}

__global__ void k_scan2(const int* __restrict__ btot, int* __restrict__ bbase,
                        int nb, int* __restrict__ offs, int n){
  int lane = threadIdx.x & 63;
  int carry = 0;
  for (int s = 0; s < nb; s += 64){
    int idx = s + lane;
    int v = (idx < nb) ? btot[idx] : 0;
    int incl = v;
    #pragma unroll
    for (int d = 1; d < 64; d <<= 1){
      int o = __shfl_up(incl, d);
      if (lane >= d) incl += o;
    }
    if (idx < nb) bbase[idx] = carry + incl - v;
    carry += __shfl(incl, 63);
  }
  if (lane == 0) offs[n] = carry;
}

__global__ void k_scan3(const int* __restrict__ loc, const int* __restrict__ bbase,
                        int* __restrict__ offs, int* __restrict__ cur, int n){
  int i = blockIdx.x * blockDim.x + threadIdx.x;
  if (i < n){
    int ex = loc[i] + bbase[i >> 10];
    offs[i] = ex;
    cur[i] = ex;
  }
}

__global__ void k_fill(const int* __restrict__ row, const int* __restrict__ col,
                       int* __restrict__ cur, int* __restrict__ srcs, int e){
  for (int i = blockIdx.x * blockDim.x + threadIdx.x; i < e; i += gridDim.x * blockDim.x){
    int c = col[i];
    int p = atomicAdd(&cur[c], 1);
    srcs[p] = row[i];
  }
}

// ---------------- scatter_mean as per-node gather: one wave per node, ILP-unrolled ----------------
__global__ void k_agg(const float* __restrict__ src, float* __restrict__ dst,
                      const int* __restrict__ offs, const int* __restrict__ srcs, int n){
  int wid = (blockIdx.x * blockDim.x + threadIdx.x) >> 6;
  int lane = threadIdx.x & 63;
  int nw = (gridDim.x * blockDim.x) >> 6;
  const float2* s2 = (const float2*)src;
  for (int node = wid; node < n; node += nw){
    int o0 = offs[node], o1 = offs[node + 1];
    float ax = 0.0f, ay = 0.0f;
    for (int base = o0; base < o1; base += 64){
      int m = o1 - base; if (m > 64) m = 64;
      int myidx = (base + lane < o1) ? srcs[base + lane] : 0;
      int j = 0;
      for (; j + 4 <= m; j += 4){
        int i0 = __shfl(myidx, j);
        int i1 = __shfl(myidx, j + 1);
        int i2 = __shfl(myidx, j + 2);
        int i3 = __shfl(myidx, j + 3);
        float2 v0 = s2[(size_t)i0 * 64 + lane];
        float2 v1 = s2[(size_t)i1 * 64 + lane];
        float2 v2 = s2[(size_t)i2 * 64 + lane];
        float2 v3 = s2[(size_t)i3 * 64 + lane];
        ax += (v0.x + v1.x) + (v2.x + v3.x);
        ay += (v0.y + v1.y) + (v2.y + v3.y);
      }
      for (; j < m; ++j){
        int s = __shfl(myidx, j);
        float2 v = s2[(size_t)s * 64 + lane];
        ax += v.x; ay += v.y;
      }
    }
    float inv = 1.0f / fmaxf((float)(o1 - o0), 1.0f);
    ((float2*)dst)[(size_t)node * 64 + lane] = make_float2(ax * inv, ay * inv);
  }
}

// ---------------- attention: logits = sum_i c_i @ U_i + lc ; softmax ----------------
__global__ void k_att(const float* __restrict__ c0, const float* __restrict__ c1,
                      const float* __restrict__ c2, const float* __restrict__ U,
                      const float* __restrict__ lc, float* __restrict__ att, int n){
  int wid = (blockIdx.x * blockDim.x + threadIdx.x) >> 6;
  int lane = threadIdx.x & 63;
  int nw = (gridDim.x * blockDim.x) >> 6;
  for (int node = wid; node < n; node += nw){
    float l0 = 0, l1 = 0, l2 = 0;
    {
      float2 v = ((const float2*)c0)[(size_t)node * 64 + lane];
      int k0 = (0 * DD + lane * 2) * 3;
      l0 += v.x * U[k0 + 0] + v.y * U[k0 + 3];
      l1 += v.x * U[k0 + 1] + v.y * U[k0 + 4];
      l2 += v.x * U[k0 + 2] + v.y * U[k0 + 5];
    }
    {
      float2 v = ((const float2*)c1)[(size_t)node * 64 + lane];
      int k0 = (1 * DD + lane * 2) * 3;
      l0 += v.x * U[k0 + 0] + v.y * U[k0 + 3];
      l1 += v.x * U[k0 + 1] + v.y * U[k0 + 4];
      l2 += v.x * U[k0 + 2] + v.y * U[k0 + 5];
    }
    {
      float2 v = ((const float2*)c2)[(size_t)node * 64 + lane];
      int k0 = (2 * DD + lane * 2) * 3;
      l0 += v.x * U[k0 + 0] + v.y * U[k0 + 3];
      l1 += v.x * U[k0 + 1] + v.y * U[k0 + 4];
      l2 += v.x * U[k0 + 2] + v.y * U[k0 + 5];
    }
    #pragma unroll
    for (int off = 32; off; off >>= 1){
      l0 += __shfl_xor(l0, off);
      l1 += __shfl_xor(l1, off);
      l2 += __shfl_xor(l2, off);
    }
    l0 += lc[0]; l1 += lc[1]; l2 += lc[2];
    float m = fmaxf(l0, fmaxf(l1, l2));
    float e0 = __expf(l0 - m), e1 = __expf(l1 - m), e2 = __expf(l2 - m);
    float inv = 1.0f / (e0 + e1 + e2);
    if (lane == 0)
      *(float4*)(att + (size_t)node * 4) = make_float4(e0 * inv, e1 * inv, e2 * inv, 0.0f);
  }
}

// ---------------- fused output GEMM: out = Z @ Vbig + (att·ob + bf) ----------------
// Z[n, i*128+k] = att[n][i] * c_i[n][k], formed at staging time.
// BK=32: LDS = Ct[64][36] (9.2KB) + Vt[32][128] (16.4KB) = 25.6KB -> 6 blocks/CU.
#define BK 32
__global__ __launch_bounds__(256) void k_out(
    const float* __restrict__ c0, const float* __restrict__ c1, const float* __restrict__ c2,
    const float* __restrict__ att, const float* __restrict__ V, const float* __restrict__ ob,
    const float* __restrict__ bf, float* __restrict__ out, int n){
  __shared__ float Ct[64][BK + 4];   // 64 nodes x 32 k (padded to 36)
  __shared__ float Vt[BK][128];      // 32 k x 128 cols
  int nbase = blockIdx.x * 64;
  int t = threadIdx.x;
  int tIdN = t >> 5;      // 0..7  -> node group of 8
  int tIdC = t & 31;      // 0..31 -> col group of 4
  float acc[8][4];
  #pragma unroll
  for (int a = 0; a < 8; ++a)
    #pragma unroll
    for (int b = 0; b < 4; ++b) acc[a][b] = 0.0f;

  for (int kt = 0; kt < 12; ++kt){
    int i = kt >> 2;              // hop
    int kc0 = (kt & 3) << 5;      // 0,32,64,96 within the hop's 128 k
    const float* cp = (i == 0) ? c0 : (i == 1) ? c1 : c2;
    __syncthreads();
    // stage Z tile (att folded in): 64 rows x 32 cols, 8 floats/thread
    {
      int r = t >> 2;              // 0..63
      int cq = (t & 3) << 3;       // 0,8,16,24
      int gn = nbase + r;
      float4 va = make_float4(0, 0, 0, 0), vb = va;
      float a = 0.0f;
      if (gn < n){
        va = *(const float4*)(cp + (size_t)gn * DD + kc0 + cq);
        vb = *(const float4*)(cp + (size_t)gn * DD + kc0 + cq + 4);
        a = att[gn * 4 + i];
      }
      *(float4*)(&Ct[r][cq])     = make_float4(va.x * a, va.y * a, va.z * a, va.w * a);
      *(float4*)(&Ct[r][cq + 4]) = make_float4(vb.x * a, vb.y * a, vb.z * a, vb.w * a);
    }
    // stage V tile: 32 rows x 128 cols, 4 float4/thread
    {
      int vr = t >> 5;             // 0..7
      int vc = (t & 31) << 2;      // 0..124
      #pragma unroll
      for (int p = 0; p < 4; ++p){
        int rr = vr + p * 8;
        *(float4*)(&Vt[rr][vc]) = *(const float4*)(V + (size_t)(i * DD + kc0 + rr) * DD + vc);
      }
    }
    __syncthreads();
    // GEMM on the tile
    #pragma unroll
    for (int kk = 0; kk < BK; kk += 4){
      float4 z[8];
      #pragma unroll
      for (int nn = 0; nn < 8; ++nn) z[nn] = *(const float4*)(&Ct[tIdN * 8 + nn][kk]);
      #pragma unroll
      for (int q = 0; q < 4; ++q){
        float4 v = *(const float4*)(&Vt[kk + q][tIdC * 4]);
        #pragma unroll
        for (int nn = 0; nn < 8; ++nn){
          float zz = (q == 0) ? z[nn].x : (q == 1) ? z[nn].y : (q == 2) ? z[nn].z : z[nn].w;
          acc[nn][0] += zz * v.x;
          acc[nn][1] += zz * v.y;
          acc[nn][2] += zz * v.z;
          acc[nn][3] += zz * v.w;
        }
      }
    }
  }
  // epilogue: bias + attention-weighted ob
  int cc = tIdC * 4;
  float4 bb = *(const float4*)(bf + cc);
  float4 o0 = *(const float4*)(ob + 0 * DD + cc);
  float4 o1 = *(const float4*)(ob + 1 * DD + cc);
  float4 o2 = *(const float4*)(ob + 2 * DD + cc);
  #pragma unroll
  for (int nn = 0; nn < 8; ++nn){
    int gn = nbase + tIdN * 8 + nn;
    if (gn < n){
      float a0 = att[gn * 4 + 0], a1 = att[gn * 4 + 1], a2 = att[gn * 4 + 2];
      float4 r;
      r.x = acc[nn][0] + bb.x + a0 * o0.x + a1 * o1.x + a2 * o2.x;
      r.y = acc[nn][1] + bb.y + a0 * o0.y + a1 * o1.y + a2 * o2.y;
      r.z = acc[nn][2] + bb.z + a0 * o0.z + a1 * o1.z + a2 * o2.z;
      r.w = acc[nn][3] + bb.w + a0 * o0.w + a1 * o1.w + a2 * o2.w;
      *(float4*)(out + (size_t)gn * DD + cc) = r;
    }
  }
}

extern "C" void kernel_launch(void* const* d_in, const int* in_sizes, int n_in,
                              void* d_out, int out_size, void* d_ws, size_t ws_size,
                              hipStream_t stream){
  const float* x   = (const float*)d_in[0];
  const int*   ei  = (const int*)d_in[1];
  const int*   dep = (const int*)d_in[2];
  const float* Wh  = (const float*)d_in[3];
  const float* bh  = (const float*)d_in[4];
  const float* Wg1 = (const float*)d_in[5];
  const float* bg1 = (const float*)d_in[6];
  const float* Wg2 = (const float*)d_in[7];
  const float* bg2 = (const float*)d_in[8];
  const float* Wa  = (const float*)d_in[9];
  const float* ba  = (const float*)d_in[10];
  const float* Wf  = (const float*)d_in[11];
  const float* bf  = (const float*)d_in[12];
  float* out = (float*)d_out;

  int N = in_sizes[0] / DD;
  int E = in_sizes[1] / 2;
  if (N <= 0) return;
  const int* row = ei;
  const int* col = ei + E;

  char* w = (char*)d_ws;
  size_t o = 0;
  auto alloc = [&](size_t bytes) -> void* {
    void* p = w + o;
    o += (bytes + 255) & ~(size_t)255;
    return p;
  };
  float* c1   = (float*)alloc((size_t)N * DD * 4);
  float* c2   = (float*)alloc((size_t)N * DD * 4);
  float* att  = (float*)alloc((size_t)N * 4 * 4);
  float* V    = (float*)alloc((size_t)3 * DD * DD * 4);
  float* ob   = (float*)alloc((size_t)3 * DD * 4);
  float* U    = (float*)alloc((size_t)3 * DD * 3 * 4);
  float* lc   = (float*)alloc(16);
  float* sw   = (float*)alloc(16);
  int*   maxd = (int*)alloc(16);
  int*   cnt  = (int*)alloc((size_t)N * 4);
  int*   offs = (int*)alloc((size_t)(N + 1) * 4);
  int*   cur  = (int*)alloc((size_t)N * 4);
  int*   srcs = (int*)alloc((size_t)E * 4);
  int*   loc  = (int*)alloc((size_t)N * 4);
  int    nb   = (N + 1023) / 1024;
  int*   btot = (int*)alloc((size_t)nb * 4);
  int*   bbase= (int*)alloc((size_t)nb * 4);

  hipMemsetAsync(maxd, 0, 4, stream);
  hipMemsetAsync(cnt, 0, (size_t)N * 4, stream);

  k_depthmax<<<128, 256, 0, stream>>>(dep, maxd, N);
  k_gate<<<1, 64, 0, stream>>>(maxd, Wg1, bg1, Wg2, bg2, ba, sw, lc, (float)N / 5000.0f);
  k_combine<<<dim3(129, 3), 128, 0, stream>>>(Wh, bh, Wf, sw, V, ob);
  k_ua<<<3, 128, 0, stream>>>(Wh, bh, Wa, sw, U, lc);
  k_hist<<<(E + 255) / 256, 256, 0, stream>>>(col, cnt, E);
  k_scan1<<<nb, 1024, 0, stream>>>(cnt, loc, btot, N);
  k_scan2<<<1, 64, 0, stream>>>(btot, bbase, nb, offs, N);
  k_scan3<<<(N + 255) / 256, 256, 0, stream>>>(loc, bbase, offs, cur, N);
  k_fill<<<(E + 255) / 256, 256, 0, stream>>>(row, col, cur, srcs, E);
  int aggBlocks = (N + 3) / 4;
  k_agg<<<aggBlocks, 256, 0, stream>>>(x, c1, offs, srcs, N);
  k_agg<<<aggBlocks, 256, 0, stream>>>(c1, c2, offs, srcs, N);
  k_att<<<aggBlocks, 256, 0, stream>>>(x, c1, c2, U, lc, att, N);
  k_out<<<(N + 63) / 64, 256, 0, stream>>>(x, c1, c2, att, V, ob, bf, out, N);
}